// Round 1
// baseline (437.930 us; speedup 1.0000x reference)
//
#include <hip/hip_runtime.h>

typedef _Float16 half8 __attribute__((ext_vector_type(8)));
typedef float floatx4 __attribute__((ext_vector_type(4)));

static constexpr int TM = 128, TN = 128, TK = 32;

__device__ __forceinline__ void gld_lds16(const void* g, void* l) {
  __builtin_amdgcn_global_load_lds(
      (const __attribute__((address_space(1))) void*)g,
      (__attribute__((address_space(3))) void*)l, 16, 0, 0);
}

// C[M,N] = A[M,K] · B[N,K]^T, f16 inputs, fp32 accum.
// MODE 0: out f16, += bias[n].  MODE 1: out f32, no bias.
template <int MODE>
__global__ __launch_bounds__(256) void gemm_bt(const _Float16* __restrict__ A,
                                               const _Float16* __restrict__ B,
                                               const float* __restrict__ bias,
                                               void* __restrict__ Cv,
                                               int M, int N, int K) {
  __shared__ _Float16 Ah[TM * TK];
  __shared__ _Float16 Bh[TN * TK];
  const int tid = threadIdx.x;
  const int lane = tid & 63;
  const int wid = tid >> 6;
  const int row0 = blockIdx.y * TM;
  const int col0 = blockIdx.x * TN;
  const int wr = (wid >> 1) * 64;  // wave's row offset inside tile
  const int wc = (wid & 1) * 64;   // wave's col offset
  const int lr = lane & 15;        // fragment row/col
  const int lk = (lane >> 4) * 8;  // fragment k offset
  floatx4 acc[4][4] = {};

  // staging: tile = 128x32 f16 = 8KB = 512 chunks of 16B; wave-uniform base + lane*16
  const int c0 = wid * 64 + lane;  // chunk for issue 0
  const int c1 = 256 + c0;         // chunk for issue 1

  for (int kt = 0; kt < K; kt += TK) {
    __syncthreads();
    {
      const _Float16* ga0 = A + (size_t)(row0 + (c0 >> 2)) * K + kt + ((c0 & 3) << 3);
      const _Float16* ga1 = A + (size_t)(row0 + (c1 >> 2)) * K + kt + ((c1 & 3) << 3);
      const _Float16* gb0 = B + (size_t)(col0 + (c0 >> 2)) * K + kt + ((c0 & 3) << 3);
      const _Float16* gb1 = B + (size_t)(col0 + (c1 >> 2)) * K + kt + ((c1 & 3) << 3);
      gld_lds16(ga0, &Ah[c0 * 8]);
      gld_lds16(ga1, &Ah[c1 * 8]);
      gld_lds16(gb0, &Bh[c0 * 8]);
      gld_lds16(gb1, &Bh[c1 * 8]);
    }
    __syncthreads();
    half8 af[4], bf[4];
#pragma unroll
    for (int m = 0; m < 4; ++m)
      af[m] = *(const half8*)&Ah[(wr + m * 16 + lr) * TK + lk];
#pragma unroll
    for (int n = 0; n < 4; ++n)
      bf[n] = *(const half8*)&Bh[(wc + n * 16 + lr) * TK + lk];
#pragma unroll
    for (int m = 0; m < 4; ++m)
#pragma unroll
      for (int n = 0; n < 4; ++n)
        acc[m][n] = __builtin_amdgcn_mfma_f32_16x16x32_f16(af[m], bf[n], acc[m][n], 0, 0, 0);
  }

  const int orow = row0 + wr + (lane >> 4) * 4;  // + m*16 + j
  const int ocol = col0 + wc + lr;               // + n*16
  if (MODE == 0) {
    _Float16* Cf = (_Float16*)Cv;
#pragma unroll
    for (int m = 0; m < 4; ++m)
#pragma unroll
      for (int n = 0; n < 4; ++n) {
        const int col = ocol + n * 16;
        const float bvv = bias[col];
#pragma unroll
        for (int j = 0; j < 4; ++j)
          Cf[(size_t)(orow + m * 16 + j) * N + col] = (_Float16)(acc[m][n][j] + bvv);
      }
  } else {
    float* Cf = (float*)Cv;
#pragma unroll
    for (int m = 0; m < 4; ++m)
#pragma unroll
      for (int n = 0; n < 4; ++n)
#pragma unroll
        for (int j = 0; j < 4; ++j)
          Cf[(size_t)(orow + m * 16 + j) * N + ocol + n * 16] = acc[m][n][j];
  }
}

__global__ void cvt_f32_f16(const float* __restrict__ in, _Float16* __restrict__ out, int n8) {
  int i = blockIdx.x * blockDim.x + threadIdx.x;
  const int stride = gridDim.x * blockDim.x;
  for (; i < n8; i += stride) {
    const float4* p = (const float4*)(in + (size_t)i * 8);
    float4 a = p[0], b = p[1];
    half8 h;
    h[0] = (_Float16)a.x; h[1] = (_Float16)a.y; h[2] = (_Float16)a.z; h[3] = (_Float16)a.w;
    h[4] = (_Float16)b.x; h[5] = (_Float16)b.y; h[6] = (_Float16)b.z; h[7] = (_Float16)b.w;
    *(half8*)(out + (size_t)i * 8) = h;
  }
}

// V[4*2048][1024] -> Vt[4][1024][2048]
__global__ __launch_bounds__(256) void transpose_v(const _Float16* __restrict__ V,
                                                   _Float16* __restrict__ Vt) {
  __shared__ _Float16 t[32][36];
  const int b = blockIdx.z;
  const int e0 = blockIdx.x * 32;
  const int s0 = blockIdx.y * 32;
  const int tid = threadIdx.x;
  const int r = tid >> 3;
  const int c4 = (tid & 7) * 4;
  const _Float16* src = V + (size_t)(b * 2048 + s0 + r) * 1024 + e0 + c4;
#pragma unroll
  for (int j = 0; j < 4; ++j) t[r][c4 + j] = src[j];
  __syncthreads();
  _Float16* dst = Vt + ((size_t)b * 1024 + e0 + r) * 2048 + s0 + c4;
#pragma unroll
  for (int j = 0; j < 4; ++j) dst[j] = t[c4 + j][r];
}

// one block per row of 2048 fp32 scores -> f16 probabilities
__global__ __launch_bounds__(256) void softmax_rows(const float* __restrict__ Srow,
                                                    _Float16* __restrict__ P) {
  __shared__ float red[4];
  const size_t row = blockIdx.x;
  const float* s = Srow + row * 2048;
  const int tid = threadIdx.x;
  float v[8];
  {
    const float4* p = (const float4*)(s + tid * 8);
    float4 a = p[0], b = p[1];
    v[0] = a.x; v[1] = a.y; v[2] = a.z; v[3] = a.w;
    v[4] = b.x; v[5] = b.y; v[6] = b.z; v[7] = b.w;
  }
  float m = v[0];
#pragma unroll
  for (int j = 1; j < 8; ++j) m = fmaxf(m, v[j]);
#pragma unroll
  for (int off = 32; off > 0; off >>= 1) m = fmaxf(m, __shfl_xor(m, off));
  if ((tid & 63) == 0) red[tid >> 6] = m;
  __syncthreads();
  m = fmaxf(fmaxf(red[0], red[1]), fmaxf(red[2], red[3]));
  float sum = 0.f;
#pragma unroll
  for (int j = 0; j < 8; ++j) { v[j] = __expf(v[j] - m); sum += v[j]; }
#pragma unroll
  for (int off = 32; off > 0; off >>= 1) sum += __shfl_xor(sum, off);
  __syncthreads();
  if ((tid & 63) == 0) red[tid >> 6] = sum;
  __syncthreads();
  sum = red[0] + red[1] + red[2] + red[3];
  const float inv = 1.0f / sum;
  half8 h;
#pragma unroll
  for (int j = 0; j < 8; ++j) h[j] = (_Float16)(v[j] * inv);
  *(half8*)(P + row * 2048 + tid * 8) = h;
}

extern "C" void kernel_launch(void* const* d_in, const int* in_sizes, int n_in,
                              void* d_out, int out_size, void* d_ws, size_t ws_size,
                              hipStream_t stream) {
  (void)in_sizes; (void)n_in; (void)out_size;
  const float* x  = (const float*)d_in[0];
  const float* Wq = (const float*)d_in[1];
  const float* bq = (const float*)d_in[2];
  const float* Wk = (const float*)d_in[3];
  const float* bk = (const float*)d_in[4];
  const float* Wv = (const float*)d_in[5];
  const float* bv = (const float*)d_in[6];
  float* out = (float*)d_out;

  char* ws = (char*)d_ws;
  size_t off = 0;
  auto alloc = [&](size_t bytes) {
    char* p = ws + off;
    off += (bytes + 255) & ~255ull;
    return p;
  };
  _Float16* x16  = (_Float16*)alloc(8192ull * 1024 * 2);
  _Float16* Wq16 = (_Float16*)alloc(1024ull * 1024 * 2);
  _Float16* Wk16 = (_Float16*)alloc(1024ull * 1024 * 2);
  _Float16* Wv16 = (_Float16*)alloc(1024ull * 1024 * 2);
  _Float16* Qf   = (_Float16*)alloc(8192ull * 1024 * 2);
  _Float16* Kf   = (_Float16*)alloc(8192ull * 1024 * 2);
  _Float16* Vf   = (_Float16*)alloc(8192ull * 1024 * 2);
  _Float16* Vt   = (_Float16*)alloc(8192ull * 1024 * 2);
  float*    Sc   = (float*)alloc(2048ull * 2048 * 4);
  _Float16* Pa   = (_Float16*)alloc(2048ull * 2048 * 2);
  if (off > ws_size) return;  // ws too small: bail cleanly (bench will show absmax fail)

  cvt_f32_f16<<<2048, 256, 0, stream>>>(x, x16, 8192 * 1024 / 8);
  cvt_f32_f16<<<512, 256, 0, stream>>>(Wq, Wq16, 1024 * 1024 / 8);
  cvt_f32_f16<<<512, 256, 0, stream>>>(Wk, Wk16, 1024 * 1024 / 8);
  cvt_f32_f16<<<512, 256, 0, stream>>>(Wv, Wv16, 1024 * 1024 / 8);

  dim3 blk(256);
  gemm_bt<0><<<dim3(1024 / TN, 8192 / TM), blk, 0, stream>>>(x16, Wq16, bq, Qf, 8192, 1024, 1024);
  gemm_bt<0><<<dim3(1024 / TN, 8192 / TM), blk, 0, stream>>>(x16, Wk16, bk, Kf, 8192, 1024, 1024);
  gemm_bt<0><<<dim3(1024 / TN, 8192 / TM), blk, 0, stream>>>(x16, Wv16, bv, Vf, 8192, 1024, 1024);
  transpose_v<<<dim3(1024 / 32, 2048 / 32, 4), blk, 0, stream>>>(Vf, Vt);

  for (int b = 0; b < 4; ++b) {
    const _Float16* Qb  = Qf + (size_t)b * 2048 * 1024;
    const _Float16* Kb  = Kf + (size_t)b * 2048 * 1024;
    const _Float16* Vtb = Vt + (size_t)b * 1024 * 2048;
    gemm_bt<1><<<dim3(2048 / TN, 2048 / TM), blk, 0, stream>>>(Qb, Kb, nullptr, Sc, 2048, 2048, 1024);
    softmax_rows<<<2048, 256, 0, stream>>>(Sc, Pa);
    gemm_bt<1><<<dim3(1024 / TN, 2048 / TM), blk, 0, stream>>>(Pa, Vtb, nullptr,
                                                               out + (size_t)b * 2048 * 1024,
                                                               2048, 1024, 2048);
  }
}

// Round 2
// 227.531 us; speedup vs baseline: 1.9247x; 1.9247x over previous
//
#include <hip/hip_runtime.h>

typedef _Float16 half8 __attribute__((ext_vector_type(8)));
typedef float floatx4 __attribute__((ext_vector_type(4)));

static constexpr int TM = 128, TN = 128, TK = 32;

__device__ __forceinline__ void gld_lds16(const void* g, void* l) {
  __builtin_amdgcn_global_load_lds(
      (const __attribute__((address_space(1))) void*)g,
      (__attribute__((address_space(3))) void*)l, 16, 0, 0);
}

// ---------------- shared GEMM body (128x128 tile, BK=32, 4 waves) -------------
// A[M,K] f16, B[N,K] f16 (i.e. C = A·B^T), fp32 accum in AGPRs.

#define GEMM_PROLOGUE()                                                        \
  __shared__ _Float16 Ah[TM * TK];                                             \
  __shared__ _Float16 Bh[TN * TK];                                             \
  const int tid = threadIdx.x;                                                 \
  const int lane = tid & 63;                                                   \
  const int wid = tid >> 6;                                                    \
  const int wr = (wid >> 1) * 64;                                              \
  const int wc = (wid & 1) * 64;                                               \
  const int lr = lane & 15;                                                    \
  const int lk = (lane >> 4) * 8;                                              \
  floatx4 acc[4][4] = {};                                                      \
  const int c0 = wid * 64 + lane;                                              \
  const int c1 = 256 + c0;

#define GEMM_KLOOP(A_, B_, K_)                                                 \
  for (int kt = 0; kt < (K_); kt += TK) {                                      \
    __syncthreads();                                                           \
    gld_lds16((A_) + (size_t)(row0 + (c0 >> 2)) * (K_) + kt + ((c0 & 3) << 3), \
              &Ah[c0 * 8]);                                                    \
    gld_lds16((A_) + (size_t)(row0 + (c1 >> 2)) * (K_) + kt + ((c1 & 3) << 3), \
              &Ah[c1 * 8]);                                                    \
    gld_lds16((B_) + (size_t)(col0 + (c0 >> 2)) * (K_) + kt + ((c0 & 3) << 3), \
              &Bh[c0 * 8]);                                                    \
    gld_lds16((B_) + (size_t)(col0 + (c1 >> 2)) * (K_) + kt + ((c1 & 3) << 3), \
              &Bh[c1 * 8]);                                                    \
    __syncthreads();                                                           \
    half8 af[4], bf[4];                                                        \
    _Pragma("unroll") for (int m = 0; m < 4; ++m)                              \
        af[m] = *(const half8*)&Ah[(wr + m * 16 + lr) * TK + lk];              \
    _Pragma("unroll") for (int n = 0; n < 4; ++n)                              \
        bf[n] = *(const half8*)&Bh[(wc + n * 16 + lr) * TK + lk];              \
    _Pragma("unroll") for (int m = 0; m < 4; ++m)                              \
        _Pragma("unroll") for (int n = 0; n < 4; ++n)                          \
            acc[m][n] = __builtin_amdgcn_mfma_f32_16x16x32_f16(                \
                af[m], bf[n], acc[m][n], 0, 0, 0);                             \
  }

// Fused QKV projection: A = x16 [8192,1024]; B selected from {Wq,Wk,Wv} by
// blockIdx.x>>3; out f16 with bias. Grid (24, 64).
__global__ __launch_bounds__(256) void gemm_qkv(
    const _Float16* __restrict__ A, const _Float16* __restrict__ Bq,
    const _Float16* __restrict__ Bk, const _Float16* __restrict__ Bv,
    const float* __restrict__ bqp, const float* __restrict__ bkp,
    const float* __restrict__ bvp, _Float16* __restrict__ Oq,
    _Float16* __restrict__ Ok, _Float16* __restrict__ Ov) {
  const int which = blockIdx.x >> 3;
  const _Float16* B = which == 0 ? Bq : (which == 1 ? Bk : Bv);
  const float* bias = which == 0 ? bqp : (which == 1 ? bkp : bvp);
  _Float16* O = which == 0 ? Oq : (which == 1 ? Ok : Ov);
  const int col0 = (blockIdx.x & 7) * TN;
  const int row0 = blockIdx.y * TM;
  constexpr int K = 1024, N = 1024;
  GEMM_PROLOGUE();
  GEMM_KLOOP(A, B, K);
  const int orow = row0 + wr + (lane >> 4) * 4;
  const int ocol = col0 + wc + lr;
#pragma unroll
  for (int m = 0; m < 4; ++m)
#pragma unroll
    for (int n = 0; n < 4; ++n) {
      const int col = ocol + n * 16;
      const float bvv = bias[col];
#pragma unroll
      for (int j = 0; j < 4; ++j)
        O[(size_t)(orow + m * 16 + j) * N + col] = (_Float16)(acc[m][n][j] + bvv);
    }
}

// Batched C = A·B^T over blockIdx.z. OUT_F16=1 -> f16 out (scores),
// OUT_F16=0 -> f32 out (attn·V).
template <int OUT_F16>
__global__ __launch_bounds__(256) void gemm_bt(
    const _Float16* __restrict__ Ab, const _Float16* __restrict__ Bb,
    void* __restrict__ Cv, int M, int N, int K, size_t sA, size_t sB, size_t sC) {
  const _Float16* A = Ab + (size_t)blockIdx.z * sA;
  const _Float16* B = Bb + (size_t)blockIdx.z * sB;
  const int col0 = blockIdx.x * TN;
  const int row0 = blockIdx.y * TM;
  GEMM_PROLOGUE();
  GEMM_KLOOP(A, B, K);
  const int orow = row0 + wr + (lane >> 4) * 4;
  const int ocol = col0 + wc + lr;
  if (OUT_F16) {
    _Float16* Cf = (_Float16*)Cv + (size_t)blockIdx.z * sC;
#pragma unroll
    for (int m = 0; m < 4; ++m)
#pragma unroll
      for (int n = 0; n < 4; ++n)
#pragma unroll
        for (int j = 0; j < 4; ++j)
          Cf[(size_t)(orow + m * 16 + j) * N + ocol + n * 16] = (_Float16)acc[m][n][j];
  } else {
    float* Cf = (float*)Cv + (size_t)blockIdx.z * sC;
#pragma unroll
    for (int m = 0; m < 4; ++m)
#pragma unroll
      for (int n = 0; n < 4; ++n)
#pragma unroll
        for (int j = 0; j < 4; ++j)
          Cf[(size_t)(orow + m * 16 + j) * N + ocol + n * 16] = acc[m][n][j];
  }
}

__global__ void cvt_f32_f16(const float* __restrict__ in, _Float16* __restrict__ out, int n8) {
  int i = blockIdx.x * blockDim.x + threadIdx.x;
  const int stride = gridDim.x * blockDim.x;
  for (; i < n8; i += stride) {
    const float4* p = (const float4*)(in + (size_t)i * 8);
    float4 a = p[0], b = p[1];
    half8 h;
    h[0] = (_Float16)a.x; h[1] = (_Float16)a.y; h[2] = (_Float16)a.z; h[3] = (_Float16)a.w;
    h[4] = (_Float16)b.x; h[5] = (_Float16)b.y; h[6] = (_Float16)b.z; h[7] = (_Float16)b.w;
    *(half8*)(out + (size_t)i * 8) = h;
  }
}

// V[4*2048][1024] -> Vt[4][1024][2048]
__global__ __launch_bounds__(256) void transpose_v(const _Float16* __restrict__ V,
                                                   _Float16* __restrict__ Vt) {
  __shared__ _Float16 t[32][36];
  const int b = blockIdx.z;
  const int e0 = blockIdx.x * 32;
  const int s0 = blockIdx.y * 32;
  const int tid = threadIdx.x;
  const int r = tid >> 3;
  const int c4 = (tid & 7) * 4;
  const _Float16* src = V + (size_t)(b * 2048 + s0 + r) * 1024 + e0 + c4;
#pragma unroll
  for (int j = 0; j < 4; ++j) t[r][c4 + j] = src[j];
  __syncthreads();
  _Float16* dst = Vt + ((size_t)b * 1024 + e0 + r) * 2048 + s0 + c4;
#pragma unroll
  for (int j = 0; j < 4; ++j) dst[j] = t[c4 + j][r];
}

// in-place row softmax over f16 scores, one block per row of 2048
__global__ __launch_bounds__(256) void softmax_rows_f16(_Float16* __restrict__ S) {
  __shared__ float red[4];
  _Float16* s = S + (size_t)blockIdx.x * 2048;
  const int tid = threadIdx.x;
  float v[8];
  {
    half8 h = *(const half8*)(s + tid * 8);
#pragma unroll
    for (int j = 0; j < 8; ++j) v[j] = (float)h[j];
  }
  float m = v[0];
#pragma unroll
  for (int j = 1; j < 8; ++j) m = fmaxf(m, v[j]);
#pragma unroll
  for (int off = 32; off > 0; off >>= 1) m = fmaxf(m, __shfl_xor(m, off));
  if ((tid & 63) == 0) red[tid >> 6] = m;
  __syncthreads();
  m = fmaxf(fmaxf(red[0], red[1]), fmaxf(red[2], red[3]));
  float sum = 0.f;
#pragma unroll
  for (int j = 0; j < 8; ++j) { v[j] = __expf(v[j] - m); sum += v[j]; }
#pragma unroll
  for (int off = 32; off > 0; off >>= 1) sum += __shfl_xor(sum, off);
  __syncthreads();
  if ((tid & 63) == 0) red[tid >> 6] = sum;
  __syncthreads();
  sum = red[0] + red[1] + red[2] + red[3];
  const float inv = 1.0f / sum;
  half8 h;
#pragma unroll
  for (int j = 0; j < 8; ++j) h[j] = (_Float16)(v[j] * inv);
  *(half8*)(s + tid * 8) = h;
}

extern "C" void kernel_launch(void* const* d_in, const int* in_sizes, int n_in,
                              void* d_out, int out_size, void* d_ws, size_t ws_size,
                              hipStream_t stream) {
  (void)in_sizes; (void)n_in; (void)out_size;
  const float* x  = (const float*)d_in[0];
  const float* Wq = (const float*)d_in[1];
  const float* bq = (const float*)d_in[2];
  const float* Wk = (const float*)d_in[3];
  const float* bk = (const float*)d_in[4];
  const float* Wv = (const float*)d_in[5];
  const float* bv = (const float*)d_in[6];
  float* out = (float*)d_out;

  char* ws = (char*)d_ws;
  size_t off = 0;
  auto alloc = [&](size_t bytes) {
    char* p = ws + off;
    off += (bytes + 255) & ~255ull;
    return p;
  };
  _Float16* x16  = (_Float16*)alloc(8192ull * 1024 * 2);
  _Float16* Wq16 = (_Float16*)alloc(1024ull * 1024 * 2);
  _Float16* Wk16 = (_Float16*)alloc(1024ull * 1024 * 2);
  _Float16* Wv16 = (_Float16*)alloc(1024ull * 1024 * 2);
  _Float16* Qf   = (_Float16*)alloc(8192ull * 1024 * 2);
  _Float16* Kf   = (_Float16*)alloc(8192ull * 1024 * 2);
  _Float16* Vf   = (_Float16*)alloc(8192ull * 1024 * 2);
  _Float16* Vt   = (_Float16*)alloc(8192ull * 1024 * 2);
  _Float16* Sc   = (_Float16*)alloc(4ull * 2048 * 2048 * 2);  // f16 scores, in-place softmax
  if (off > ws_size) return;

  cvt_f32_f16<<<2048, 256, 0, stream>>>(x, x16, 8192 * 1024 / 8);
  cvt_f32_f16<<<512, 256, 0, stream>>>(Wq, Wq16, 1024 * 1024 / 8);
  cvt_f32_f16<<<512, 256, 0, stream>>>(Wk, Wk16, 1024 * 1024 / 8);
  cvt_f32_f16<<<512, 256, 0, stream>>>(Wv, Wv16, 1024 * 1024 / 8);

  dim3 blk(256);
  gemm_qkv<<<dim3(24, 64), blk, 0, stream>>>(x16, Wq16, Wk16, Wv16, bq, bk, bv, Qf, Kf, Vf);
  transpose_v<<<dim3(32, 64, 4), blk, 0, stream>>>(Vf, Vt);

  // scores: [b] Q[2048,1024] · K^T -> Sc f16 [2048,2048]
  gemm_bt<1><<<dim3(16, 16, 4), blk, 0, stream>>>(Qf, Kf, Sc, 2048, 2048, 1024,
                                                  2048ull * 1024, 2048ull * 1024,
                                                  2048ull * 2048);
  softmax_rows_f16<<<8192, 256, 0, stream>>>(Sc);
  // out: [b] P[2048,2048] · Vt^T -> out f32 [2048,1024]
  gemm_bt<0><<<dim3(8, 16, 4), blk, 0, stream>>>(Sc, Vt, out, 2048, 1024, 2048,
                                                 2048ull * 2048, 1024ull * 2048,
                                                 2048ull * 1024);
}

// Round 3
// 201.680 us; speedup vs baseline: 2.1714x; 1.1282x over previous
//
#include <hip/hip_runtime.h>

typedef _Float16 half8 __attribute__((ext_vector_type(8)));
typedef float floatx4 __attribute__((ext_vector_type(4)));

__device__ __forceinline__ void gld_lds16(const void* g, void* l) {
  __builtin_amdgcn_global_load_lds(
      (const __attribute__((address_space(1))) void*)g,
      (__attribute__((address_space(3))) void*)l, 16, 0, 0);
}

// ============ 256x256 8-phase f16 GEMM, C = A·B^T, fp32 accum ============
// BK=64, 8 waves (2M x 4N), 512 threads. LDS 128 KiB: 2 buf x (A 256x64 + B
// 256x64) f16, XOR-granule swizzle (g ^= row&7) on 16B granules.
// Schedule per K-tile t (buffer buf=t&1):
//  P1: ds A(qm0)+B(qn0); stage (t+1)A0->buf^1 | bar; lgkm0; 16 MFMA; bar
//  P2: ds B(qn1);        stage (t+1)A1->buf^1 | bar; lgkm0; 16 MFMA; bar
//  P3: ds A(qm1);        stage (t+2)B0->buf   | bar; lgkm0; 16 MFMA; bar
//  P4:                   stage (t+2)B1->buf; vmcnt(4|0) | bar; 16 MFMA; bar
// Raw s_barrier (no implicit vmcnt-drain). vmcnt(4) leaves (t+2)B in flight.

#define QUAD(qm, qn)                                                           \
  _Pragma("unroll") for (int mf = 0; mf < 4; ++mf)                             \
  _Pragma("unroll") for (int nf = 0; nf < 2; ++nf)                             \
  _Pragma("unroll") for (int kk = 0; kk < 2; ++kk)                             \
    acc[(qm)*4+mf][(qn)*2+nf] = __builtin_amdgcn_mfma_f32_16x16x32_f16(        \
        aF[mf*2+kk], ((qn) ? bF1 : bF0)[nf*2+kk], acc[(qm)*4+mf][(qn)*2+nf],   \
        0, 0, 0);

#define PHASE_MFMA(QM, QN, LG)                                                 \
  __builtin_amdgcn_s_barrier();                                                \
  if (LG) asm volatile("s_waitcnt lgkmcnt(0)" ::: "memory");                   \
  __builtin_amdgcn_sched_barrier(0);                                           \
  __builtin_amdgcn_s_setprio(1);                                               \
  QUAD(QM, QN);                                                                \
  __builtin_amdgcn_s_setprio(0);                                               \
  __builtin_amdgcn_sched_barrier(0);                                           \
  __builtin_amdgcn_s_barrier();

// MODE 0: QKV proj  A=x16[8192,1024] B=W16[3][1024,1024] -> f16 + bias, 384 wg
// MODE 1: scores    A=Q[z] B=K[z] K=1024 -> f16, 256 wg
// MODE 2: attnV     A=P[z] (stride 2048) B=Vt[z] K=2048 -> f32, 128 wg
template <int MODE>
__global__ __launch_bounds__(512, 2) void gemm8p(
    const _Float16* __restrict__ Ag, const _Float16* __restrict__ Bg,
    void* __restrict__ Cg, const float* __restrict__ bq,
    const float* __restrict__ bk, const float* __restrict__ bv) {
  constexpr int KS = (MODE == 2) ? 2048 : 1024;  // row stride of A and B
  constexpr int NK = (MODE == 2) ? 32 : 16;      // K-tiles of 64
  constexpr int NWG = (MODE == 0) ? 384 : (MODE == 1 ? 256 : 128);

  int g = (int)blockIdx.x;
  g = (g & 7) * (NWG / 8) + (g >> 3);  // XCD swizzle (NWG % 8 == 0)

  const _Float16* Ap;
  const _Float16* Bp;
  _Float16* C16 = nullptr;
  float* C32 = nullptr;
  const float* bias = nullptr;
  int row0, col0, cstride;
  if constexpr (MODE == 0) {
    const int tm = g / 12, cb = g % 12, which = cb >> 2;
    row0 = tm * 256; col0 = (cb & 3) * 256;
    Ap = Ag + (size_t)row0 * 1024;
    Bp = Bg + (size_t)which * 1048576 + (size_t)col0 * 1024;
    bias = which == 0 ? bq : (which == 1 ? bk : bv);
    C16 = (_Float16*)Cg + (size_t)which * 8388608;
    cstride = 1024;
  } else if constexpr (MODE == 1) {
    const int z = g >> 6, r = g & 63, tm = r >> 3, tn = r & 7;
    row0 = tm * 256; col0 = tn * 256;
    Ap = Ag + (size_t)z * 2097152 + (size_t)row0 * 1024;
    Bp = Bg + (size_t)z * 2097152 + (size_t)col0 * 1024;
    C16 = (_Float16*)Cg + (size_t)z * 4194304;
    cstride = 2048;
  } else {
    const int b = g >> 5, r = g & 31, tm = r >> 2, tn = r & 3;
    row0 = tm * 256; col0 = tn * 256;
    Ap = Ag + (size_t)b * 4194304 + (size_t)row0 * 2048;
    Bp = Bg + (size_t)b * 2097152 + (size_t)col0 * 2048;
    C32 = (float*)Cg + (size_t)b * 2097152;
    cstride = 1024;
  }

  __shared__ _Float16 lds[65536];  // 128 KiB
  const int tid = threadIdx.x;
  const int lane = tid & 63;
  const int wid = tid >> 6;
  const int wave_m = wid >> 2;  // 0..1
  const int wave_n = wid & 3;   // 0..3
  const int fr = lane & 15;
  // staging constants: slot tid holds logical granule (tid&7)^((tid>>3)&7)
  const int srow = tid >> 3;
  const int sgl = (((tid & 7) ^ ((tid >> 3) & 7)) << 3);
  // frag-read granule offsets (elements), kk=0/1: g = (kk*4+u)^(row&7)
  const int u = lane >> 4, w7 = lane & 7;
  const int k0e = ((u ^ w7) << 3);
  const int k1e = (((4 + u) ^ w7) << 3);

  floatx4 acc[8][4] = {};
  half8 aF[8];   // [mf][kk] for current qm half
  half8 bF0[4];  // qn=0: [nf][kk]
  half8 bF1[4];  // qn=1

  // stage half-tile h (128 rows) of A/B at k-offset kt into LDS base (elems)
  auto stage = [&](const _Float16* Gp, int h, int kt, int basee) {
    const _Float16* g0 = Gp + (size_t)(h * 128 + srow) * KS + kt + sgl;
    gld_lds16(g0, &lds[basee + h * 8192 + tid * 8]);
    gld_lds16(g0 + (size_t)64 * KS, &lds[basee + h * 8192 + 4096 + tid * 8]);
  };
  auto ldA = [&](int bufe, int qm) {
    const int base = bufe + (wave_m * 128 + qm * 64 + fr) * 64;
#pragma unroll
    for (int mf = 0; mf < 4; ++mf) {
      aF[mf * 2 + 0] = *(const half8*)&lds[base + mf * 1024 + k0e];
      aF[mf * 2 + 1] = *(const half8*)&lds[base + mf * 1024 + k1e];
    }
  };
  auto ldB = [&](half8* bF, int bufe, int qn) {
    const int base = bufe + 16384 + (wave_n * 64 + qn * 32 + fr) * 64;
#pragma unroll
    for (int nf = 0; nf < 2; ++nf) {
      bF[nf * 2 + 0] = *(const half8*)&lds[base + nf * 1024 + k0e];
      bF[nf * 2 + 1] = *(const half8*)&lds[base + nf * 1024 + k1e];
    }
  };

  // prologue: K0 {A0,A1,B0,B1} -> buf0; K1 {B0,B1} -> buf1
  stage(Ap, 0, 0, 0);
  stage(Ap, 1, 0, 0);
  stage(Bp, 0, 0, 16384);
  stage(Bp, 1, 0, 16384);
  stage(Bp, 0, 64, 32768 + 16384);
  stage(Bp, 1, 64, 32768 + 16384);
  asm volatile("s_waitcnt vmcnt(4)" ::: "memory");
  __builtin_amdgcn_s_barrier();

  int buf = 0;
#pragma unroll 1
  for (int t = 0; t < NK; ++t) {
    const int kt = t * 64;
    const int bufe = buf * 32768;
    const int obufe = (buf ^ 1) * 32768;
    // P1
    ldA(bufe, 0);
    ldB(bF0, bufe, 0);
    if (t + 1 < NK) stage(Ap, 0, kt + 64, obufe);
    PHASE_MFMA(0, 0, 1);
    // P2
    ldB(bF1, bufe, 1);
    if (t + 1 < NK) stage(Ap, 1, kt + 64, obufe);
    PHASE_MFMA(0, 1, 1);
    // P3
    ldA(bufe, 1);
    if (t + 2 < NK) stage(Bp, 0, kt + 128, bufe + 16384);
    PHASE_MFMA(1, 0, 1);
    // P4
    if (t + 2 < NK) stage(Bp, 1, kt + 128, bufe + 16384);
    if (t + 1 < NK) {
      if (t + 2 < NK) asm volatile("s_waitcnt vmcnt(4)" ::: "memory");
      else            asm volatile("s_waitcnt vmcnt(0)" ::: "memory");
    }
    PHASE_MFMA(1, 1, 0);
    buf ^= 1;
  }

  // epilogue: C row = r0 + m*16 + j, col = c0 + n*16
  const int r0 = row0 + wave_m * 128 + (lane >> 4) * 4;
  const int c0 = col0 + wave_n * 64 + fr;
#pragma unroll
  for (int m = 0; m < 8; ++m)
#pragma unroll
    for (int n = 0; n < 4; ++n) {
      const int col = c0 + n * 16;
      float badd = 0.f;
      if constexpr (MODE == 0) badd = bias[col];
#pragma unroll
      for (int j = 0; j < 4; ++j) {
        const int row = r0 + m * 16 + j;
        if constexpr (MODE == 2)
          C32[(size_t)row * cstride + col] = acc[m][n][j];
        else
          C16[(size_t)row * cstride + col] = (_Float16)(acc[m][n][j] + badd);
      }
    }
}

// ---------------------------------------------------------------------------
__global__ void cvt_f32_f16(const float* __restrict__ in, _Float16* __restrict__ out, int n8) {
  int i = blockIdx.x * blockDim.x + threadIdx.x;
  const int stride = gridDim.x * blockDim.x;
  for (; i < n8; i += stride) {
    const float4* p = (const float4*)(in + (size_t)i * 8);
    float4 a = p[0], b = p[1];
    half8 h;
    h[0] = (_Float16)a.x; h[1] = (_Float16)a.y; h[2] = (_Float16)a.z; h[3] = (_Float16)a.w;
    h[4] = (_Float16)b.x; h[5] = (_Float16)b.y; h[6] = (_Float16)b.z; h[7] = (_Float16)b.w;
    *(half8*)(out + (size_t)i * 8) = h;
  }
}

// V[4*2048][1024] -> Vt[4][1024][2048]
__global__ __launch_bounds__(256) void transpose_v(const _Float16* __restrict__ V,
                                                   _Float16* __restrict__ Vt) {
  __shared__ _Float16 t[32][36];
  const int b = blockIdx.z;
  const int e0 = blockIdx.x * 32;
  const int s0 = blockIdx.y * 32;
  const int tid = threadIdx.x;
  const int r = tid >> 3;
  const int c4 = (tid & 7) * 4;
  const _Float16* src = V + (size_t)(b * 2048 + s0 + r) * 1024 + e0 + c4;
#pragma unroll
  for (int j = 0; j < 4; ++j) t[r][c4 + j] = src[j];
  __syncthreads();
  _Float16* dst = Vt + ((size_t)b * 1024 + e0 + r) * 2048 + s0 + c4;
#pragma unroll
  for (int j = 0; j < 4; ++j) dst[j] = t[c4 + j][r];
}

// in-place row softmax over f16 scores, one block per row of 2048
__global__ __launch_bounds__(256) void softmax_rows_f16(_Float16* __restrict__ S) {
  __shared__ float red[4];
  _Float16* s = S + (size_t)blockIdx.x * 2048;
  const int tid = threadIdx.x;
  float v[8];
  {
    half8 h = *(const half8*)(s + tid * 8);
#pragma unroll
    for (int j = 0; j < 8; ++j) v[j] = (float)h[j];
  }
  float m = v[0];
#pragma unroll
  for (int j = 1; j < 8; ++j) m = fmaxf(m, v[j]);
#pragma unroll
  for (int off = 32; off > 0; off >>= 1) m = fmaxf(m, __shfl_xor(m, off));
  if ((tid & 63) == 0) red[tid >> 6] = m;
  __syncthreads();
  m = fmaxf(fmaxf(red[0], red[1]), fmaxf(red[2], red[3]));
  float sum = 0.f;
#pragma unroll
  for (int j = 0; j < 8; ++j) { v[j] = __expf(v[j] - m); sum += v[j]; }
#pragma unroll
  for (int off = 32; off > 0; off >>= 1) sum += __shfl_xor(sum, off);
  __syncthreads();
  if ((tid & 63) == 0) red[tid >> 6] = sum;
  __syncthreads();
  sum = red[0] + red[1] + red[2] + red[3];
  const float inv = 1.0f / sum;
  half8 h;
#pragma unroll
  for (int j = 0; j < 8; ++j) h[j] = (_Float16)(v[j] * inv);
  *(half8*)(s + tid * 8) = h;
}

extern "C" void kernel_launch(void* const* d_in, const int* in_sizes, int n_in,
                              void* d_out, int out_size, void* d_ws, size_t ws_size,
                              hipStream_t stream) {
  (void)in_sizes; (void)n_in; (void)out_size;
  const float* x  = (const float*)d_in[0];
  const float* Wq = (const float*)d_in[1];
  const float* bq = (const float*)d_in[2];
  const float* Wk = (const float*)d_in[3];
  const float* bk = (const float*)d_in[4];
  const float* Wv = (const float*)d_in[5];
  const float* bv = (const float*)d_in[6];
  float* out = (float*)d_out;

  char* ws = (char*)d_ws;
  size_t off = 0;
  auto alloc = [&](size_t bytes) {
    char* p = ws + off;
    off += (bytes + 255) & ~255ull;
    return p;
  };
  _Float16* x16  = (_Float16*)alloc(8192ull * 1024 * 2);       // 16 MB
  _Float16* W16  = (_Float16*)alloc(3ull * 1024 * 1024 * 2);   // 6 MB (q|k|v)
  _Float16* QKV  = (_Float16*)alloc(3ull * 8192 * 1024 * 2);   // 48 MB (Q|K|V)
  _Float16* Vt   = (_Float16*)alloc(8192ull * 1024 * 2);       // 16 MB
  _Float16* Sc   = (_Float16*)alloc(4ull * 2048 * 2048 * 2);   // 32 MB
  if (off > ws_size) return;

  cvt_f32_f16<<<2048, 256, 0, stream>>>(x, x16, 8192 * 1024 / 8);
  cvt_f32_f16<<<512, 256, 0, stream>>>(Wq, W16, 1024 * 1024 / 8);
  cvt_f32_f16<<<512, 256, 0, stream>>>(Wk, W16 + 1048576, 1024 * 1024 / 8);
  cvt_f32_f16<<<512, 256, 0, stream>>>(Wv, W16 + 2097152, 1024 * 1024 / 8);

  gemm8p<0><<<384, 512, 0, stream>>>(x16, W16, QKV, bq, bk, bv);
  transpose_v<<<dim3(32, 64, 4), 256, 0, stream>>>(QKV + 2ull * 8388608, Vt);

  gemm8p<1><<<256, 512, 0, stream>>>(QKV, QKV + 8388608, Sc, nullptr, nullptr, nullptr);
  softmax_rows_f16<<<8192, 256, 0, stream>>>(Sc);
  gemm8p<2><<<128, 512, 0, stream>>>(Sc, Vt, out, nullptr, nullptr, nullptr);
}

// Round 4
// 174.027 us; speedup vs baseline: 2.5164x; 1.1589x over previous
//
#include <hip/hip_runtime.h>

typedef _Float16 half8 __attribute__((ext_vector_type(8)));
typedef float floatx4 __attribute__((ext_vector_type(4)));

__device__ __forceinline__ void gld_lds16(const void* g, void* l) {
  __builtin_amdgcn_global_load_lds(
      (const __attribute__((address_space(1))) void*)g,
      (__attribute__((address_space(3))) void*)l, 16, 0, 0);
}

#define PHASE_MFMA_PRE()                                                       \
  __builtin_amdgcn_s_barrier();                                                \
  asm volatile("s_waitcnt lgkmcnt(0)" ::: "memory");                           \
  __builtin_amdgcn_sched_barrier(0);                                           \
  __builtin_amdgcn_s_setprio(1);

#define PHASE_MFMA_POST()                                                      \
  __builtin_amdgcn_s_setprio(0);                                               \
  __builtin_amdgcn_sched_barrier(0);                                           \
  __builtin_amdgcn_s_barrier();

// ============ 256x256 4-phase f16 GEMM (scores): C = A·B^T, f16 out =========
#define QUAD(qm, qn)                                                           \
  _Pragma("unroll") for (int mf = 0; mf < 4; ++mf)                             \
  _Pragma("unroll") for (int nf = 0; nf < 2; ++nf)                             \
  _Pragma("unroll") for (int kk = 0; kk < 2; ++kk)                             \
    acc[(qm)*4+mf][(qn)*2+nf] = __builtin_amdgcn_mfma_f32_16x16x32_f16(        \
        aF[mf*2+kk], ((qn) ? bF1 : bF0)[nf*2+kk], acc[(qm)*4+mf][(qn)*2+nf],   \
        0, 0, 0);

// scores: A=Q[z], B=K[z], K=1024 -> f16 scores [z][2048][2048]; 256 wgs
__global__ __launch_bounds__(512, 2) void gemm8p_sc(const _Float16* __restrict__ Ag,
                                                    const _Float16* __restrict__ Bg,
                                                    _Float16* __restrict__ Cg) {
  constexpr int KS = 1024, NK = 16, NWG = 256;
  int g = (int)blockIdx.x;
  g = (g & 7) * (NWG / 8) + (g >> 3);
  const int z = g >> 6, r = g & 63, tm = r >> 3, tn = r & 7;
  const int row0 = tm * 256, col0 = tn * 256;
  const _Float16* Ap = Ag + (size_t)z * 2097152 + (size_t)row0 * 1024;
  const _Float16* Bp = Bg + (size_t)z * 2097152 + (size_t)col0 * 1024;
  _Float16* C16 = Cg + (size_t)z * 4194304;

  __shared__ _Float16 lds[65536];
  const int tid = threadIdx.x;
  const int lane = tid & 63;
  const int wid = tid >> 6;
  const int wave_m = wid >> 2, wave_n = wid & 3;
  const int fr = lane & 15;
  const int srow = tid >> 3;
  const int sgl = (((tid & 7) ^ ((tid >> 3) & 7)) << 3);
  const int u = lane >> 4, w7 = lane & 7;
  const int k0e = ((u ^ w7) << 3);
  const int k1e = (((4 + u) ^ w7) << 3);

  floatx4 acc[8][4] = {};
  half8 aF[8], bF0[4], bF1[4];

  auto stage = [&](const _Float16* Gp, int h, int kt, int basee) {
    const _Float16* g0 = Gp + (size_t)(h * 128 + srow) * KS + kt + sgl;
    gld_lds16(g0, &lds[basee + h * 8192 + tid * 8]);
    gld_lds16(g0 + (size_t)64 * KS, &lds[basee + h * 8192 + 4096 + tid * 8]);
  };
  auto ldA = [&](int bufe, int qm) {
    const int base = bufe + (wave_m * 128 + qm * 64 + fr) * 64;
#pragma unroll
    for (int mf = 0; mf < 4; ++mf) {
      aF[mf * 2 + 0] = *(const half8*)&lds[base + mf * 1024 + k0e];
      aF[mf * 2 + 1] = *(const half8*)&lds[base + mf * 1024 + k1e];
    }
  };
  auto ldB = [&](half8* bF, int bufe, int qn) {
    const int base = bufe + 16384 + (wave_n * 64 + qn * 32 + fr) * 64;
#pragma unroll
    for (int nf = 0; nf < 2; ++nf) {
      bF[nf * 2 + 0] = *(const half8*)&lds[base + nf * 1024 + k0e];
      bF[nf * 2 + 1] = *(const half8*)&lds[base + nf * 1024 + k1e];
    }
  };

  stage(Ap, 0, 0, 0);
  stage(Ap, 1, 0, 0);
  stage(Bp, 0, 0, 16384);
  stage(Bp, 1, 0, 16384);
  stage(Bp, 0, 64, 32768 + 16384);
  stage(Bp, 1, 64, 32768 + 16384);
  asm volatile("s_waitcnt vmcnt(4)" ::: "memory");
  __builtin_amdgcn_s_barrier();

  int buf = 0;
#pragma unroll 1
  for (int t = 0; t < NK; ++t) {
    const int kt = t * 64;
    const int bufe = buf * 32768;
    const int obufe = (buf ^ 1) * 32768;
    ldA(bufe, 0);
    ldB(bF0, bufe, 0);
    if (t + 1 < NK) stage(Ap, 0, kt + 64, obufe);
    PHASE_MFMA_PRE(); QUAD(0, 0); PHASE_MFMA_POST();
    ldB(bF1, bufe, 1);
    if (t + 1 < NK) stage(Ap, 1, kt + 64, obufe);
    PHASE_MFMA_PRE(); QUAD(0, 1); PHASE_MFMA_POST();
    ldA(bufe, 1);
    if (t + 2 < NK) stage(Bp, 0, kt + 128, bufe + 16384);
    PHASE_MFMA_PRE(); QUAD(1, 0); PHASE_MFMA_POST();
    if (t + 2 < NK) stage(Bp, 1, kt + 128, bufe + 16384);
    if (t + 1 < NK) {
      if (t + 2 < NK) asm volatile("s_waitcnt vmcnt(4)" ::: "memory");
      else            asm volatile("s_waitcnt vmcnt(0)" ::: "memory");
    }
    __builtin_amdgcn_s_barrier();
    __builtin_amdgcn_s_setprio(1);
    QUAD(1, 1);
    __builtin_amdgcn_s_setprio(0);
    __builtin_amdgcn_sched_barrier(0);
    __builtin_amdgcn_s_barrier();
    buf ^= 1;
  }

  const int r0 = row0 + wave_m * 128 + (lane >> 4) * 4;
  const int c0 = col0 + wave_n * 64 + fr;
#pragma unroll
  for (int m = 0; m < 8; ++m)
#pragma unroll
    for (int n = 0; n < 4; ++n)
#pragma unroll
      for (int j = 0; j < 4; ++j)
        C16[(size_t)(r0 + m * 16 + j) * 2048 + c0 + n * 16] = (_Float16)acc[m][n][j];
}

// ======== 256x128-tile 2-phase f16 GEMM: C = A·B^T, per-wave 64x64 ==========
// MODE 0: QKV  A=x16[8192,1024], B=W16[3][1024,1024] -> f16+bias, 768 wgs
// MODE 2: PV   A=Sc[b][2048,2048], B=Vt[b][1024,2048] -> f32, 256 wgs
#define QUAD2(qn)                                                              \
  _Pragma("unroll") for (int mf = 0; mf < 4; ++mf)                             \
  _Pragma("unroll") for (int nf = 0; nf < 2; ++nf)                             \
  _Pragma("unroll") for (int kk = 0; kk < 2; ++kk)                             \
    acc[mf][(qn)*2+nf] = __builtin_amdgcn_mfma_f32_16x16x32_f16(               \
        aF[mf*2+kk], ((qn) ? bF1 : bF0)[nf*2+kk], acc[mf][(qn)*2+nf], 0, 0, 0);

template <int MODE>
__global__ __launch_bounds__(512, 2) void gemm2p(
    const _Float16* __restrict__ Ag, const _Float16* __restrict__ Bg,
    void* __restrict__ Cg, const float* __restrict__ bq,
    const float* __restrict__ bk, const float* __restrict__ bv) {
  constexpr int KS = (MODE == 2) ? 2048 : 1024;
  constexpr int NK = (MODE == 2) ? 32 : 16;
  constexpr int NWG = (MODE == 2) ? 256 : 768;

  int g = (int)blockIdx.x;
  g = (g & 7) * (NWG / 8) + (g >> 3);

  const _Float16* Ap;
  const _Float16* Bp;
  _Float16* C16 = nullptr;
  float* C32 = nullptr;
  const float* bias = nullptr;
  int row0, col0;
  if constexpr (MODE == 0) {
    const int tm = g / 24, c = g % 24, which = c >> 3, tn = c & 7;
    row0 = tm * 256; col0 = tn * 128;
    Ap = Ag + (size_t)row0 * 1024;
    Bp = Bg + (size_t)which * 1048576 + (size_t)col0 * 1024;
    bias = which == 0 ? bq : (which == 1 ? bk : bv);
    C16 = (_Float16*)Cg + (size_t)which * 8388608;
  } else {
    const int b = g >> 6, r = g & 63, tm = r >> 3, tn = r & 7;
    row0 = tm * 256; col0 = tn * 128;
    Ap = Ag + (size_t)b * 4194304 + (size_t)row0 * 2048;
    Bp = Bg + (size_t)b * 2097152 + (size_t)col0 * 2048;
    C32 = (float*)Cg + (size_t)b * 2097152;
  }

  // LDS: A[2][16384] @ 0/16384 ; B[2][8192] @ 32768/40960  (96 KiB)
  __shared__ _Float16 lds[49152];
  const int tid = threadIdx.x;
  const int lane = tid & 63;
  const int wid = tid >> 6;
  const int wave_m = wid >> 1;  // 0..3 (64-row band)
  const int wave_n = wid & 1;   // 0..1 (64-col band)
  const int fr = lane & 15;
  const int srow = tid >> 3;
  const int sgl = (((tid & 7) ^ ((tid >> 3) & 7)) << 3);
  const int u = lane >> 4, w7 = lane & 7;
  const int k0e = ((u ^ w7) << 3);
  const int k1e = (((4 + u) ^ w7) << 3);

  floatx4 acc[4][4] = {};
  half8 aF[8], bF0[4], bF1[4];

  auto stage = [&](const _Float16* Gp, int h, int kt, int basee) {
    const _Float16* g0 = Gp + (size_t)(h * 128 + srow) * KS + kt + sgl;
    gld_lds16(g0, &lds[basee + h * 8192 + tid * 8]);
    gld_lds16(g0 + (size_t)64 * KS, &lds[basee + h * 8192 + 4096 + tid * 8]);
  };
  auto ldA = [&](int bufA) {
    const int base = bufA + (wave_m * 64 + fr) * 64;
#pragma unroll
    for (int mf = 0; mf < 4; ++mf) {
      aF[mf * 2 + 0] = *(const half8*)&lds[base + mf * 1024 + k0e];
      aF[mf * 2 + 1] = *(const half8*)&lds[base + mf * 1024 + k1e];
    }
  };
  auto ldB = [&](half8* bF, int bufB, int qn) {
    const int base = bufB + (wave_n * 64 + qn * 32 + fr) * 64;
#pragma unroll
    for (int nf = 0; nf < 2; ++nf) {
      bF[nf * 2 + 0] = *(const half8*)&lds[base + nf * 1024 + k0e];
      bF[nf * 2 + 1] = *(const half8*)&lds[base + nf * 1024 + k1e];
    }
  };

  // prologue: tile0 A+B -> buf0, tile1 B -> buf1
  stage(Ap, 0, 0, 0);
  stage(Ap, 1, 0, 0);
  stage(Bp, 0, 0, 32768);
  stage(Bp, 0, 64, 40960);
  asm volatile("s_waitcnt vmcnt(2)" ::: "memory");
  __builtin_amdgcn_s_barrier();

  int buf = 0;
#pragma unroll 1
  for (int t = 0; t < NK; ++t) {
    const int kt = t * 64;
    const int bufA = buf * 16384;
    const int obufA = (buf ^ 1) * 16384;
    const int bufB = 32768 + buf * 8192;
    // P1
    ldA(bufA);
    ldB(bF0, bufB, 0);
    if (t + 1 < NK) stage(Ap, 0, kt + 64, obufA);
    PHASE_MFMA_PRE(); QUAD2(0); PHASE_MFMA_POST();
    // P2
    ldB(bF1, bufB, 1);
    if (t + 1 < NK) stage(Ap, 1, kt + 64, obufA);
    __builtin_amdgcn_s_barrier();
    asm volatile("s_waitcnt lgkmcnt(0)" ::: "memory");
    __builtin_amdgcn_sched_barrier(0);
    if (t + 2 < NK) stage(Bp, 0, kt + 128, bufB);  // reads of bufB done (lgkm0)
    __builtin_amdgcn_s_setprio(1);
    QUAD2(1);
    __builtin_amdgcn_s_setprio(0);
    __builtin_amdgcn_sched_barrier(0);
    if (t + 1 < NK) {
      if (t + 2 < NK) asm volatile("s_waitcnt vmcnt(2)" ::: "memory");
      else            asm volatile("s_waitcnt vmcnt(0)" ::: "memory");
    }
    __builtin_amdgcn_s_barrier();
    buf ^= 1;
  }

  const int r0 = row0 + wave_m * 64 + (lane >> 4) * 4;
  const int c0 = col0 + wave_n * 64 + fr;
#pragma unroll
  for (int m = 0; m < 4; ++m)
#pragma unroll
    for (int n = 0; n < 4; ++n) {
      const int col = c0 + n * 16;
      float badd = 0.f;
      if constexpr (MODE == 0) badd = bias[col];
#pragma unroll
      for (int j = 0; j < 4; ++j) {
        const int row = r0 + m * 16 + j;
        if constexpr (MODE == 2)
          C32[(size_t)row * 1024 + col] = acc[m][n][j];
        else
          C16[(size_t)row * 1024 + col] = (_Float16)(acc[m][n][j] + badd);
      }
    }
}

// ---------------------------------------------------------------------------
__global__ void cvt_f32_f16(const float* __restrict__ in, _Float16* __restrict__ out, int n8) {
  int i = blockIdx.x * blockDim.x + threadIdx.x;
  const int stride = gridDim.x * blockDim.x;
  for (; i < n8; i += stride) {
    const float4* p = (const float4*)(in + (size_t)i * 8);
    float4 a = p[0], b = p[1];
    half8 h;
    h[0] = (_Float16)a.x; h[1] = (_Float16)a.y; h[2] = (_Float16)a.z; h[3] = (_Float16)a.w;
    h[4] = (_Float16)b.x; h[5] = (_Float16)b.y; h[6] = (_Float16)b.z; h[7] = (_Float16)b.w;
    *(half8*)(out + (size_t)i * 8) = h;
  }
}

// 3 weight matrices f32->f16 in one dispatch; grid (512,3)
__global__ void cvt3_w(const float* __restrict__ wq, const float* __restrict__ wk,
                       const float* __restrict__ wv, _Float16* __restrict__ out) {
  const float* in = blockIdx.y == 0 ? wq : (blockIdx.y == 1 ? wk : wv);
  _Float16* o = out + (size_t)blockIdx.y * 1048576;
  const int i = blockIdx.x * blockDim.x + threadIdx.x;
  const float4* p = (const float4*)(in + (size_t)i * 8);
  float4 a = p[0], b = p[1];
  half8 h;
  h[0] = (_Float16)a.x; h[1] = (_Float16)a.y; h[2] = (_Float16)a.z; h[3] = (_Float16)a.w;
  h[4] = (_Float16)b.x; h[5] = (_Float16)b.y; h[6] = (_Float16)b.z; h[7] = (_Float16)b.w;
  *(half8*)(o + (size_t)i * 8) = h;
}

// V[4*2048][1024] -> Vt[4][1024][2048]
__global__ __launch_bounds__(256) void transpose_v(const _Float16* __restrict__ V,
                                                   _Float16* __restrict__ Vt) {
  __shared__ _Float16 t[32][36];
  const int b = blockIdx.z;
  const int e0 = blockIdx.x * 32;
  const int s0 = blockIdx.y * 32;
  const int tid = threadIdx.x;
  const int r = tid >> 3;
  const int c4 = (tid & 7) * 4;
  const _Float16* src = V + (size_t)(b * 2048 + s0 + r) * 1024 + e0 + c4;
#pragma unroll
  for (int j = 0; j < 4; ++j) t[r][c4 + j] = src[j];
  __syncthreads();
  _Float16* dst = Vt + ((size_t)b * 1024 + e0 + r) * 2048 + s0 + c4;
#pragma unroll
  for (int j = 0; j < 4; ++j) dst[j] = t[c4 + j][r];
}

// in-place row softmax over f16 scores, one block per row of 2048
__global__ __launch_bounds__(256) void softmax_rows_f16(_Float16* __restrict__ S) {
  __shared__ float red[4];
  _Float16* s = S + (size_t)blockIdx.x * 2048;
  const int tid = threadIdx.x;
  float v[8];
  {
    half8 h = *(const half8*)(s + tid * 8);
#pragma unroll
    for (int j = 0; j < 8; ++j) v[j] = (float)h[j];
  }
  float m = v[0];
#pragma unroll
  for (int j = 1; j < 8; ++j) m = fmaxf(m, v[j]);
#pragma unroll
  for (int off = 32; off > 0; off >>= 1) m = fmaxf(m, __shfl_xor(m, off));
  if ((tid & 63) == 0) red[tid >> 6] = m;
  __syncthreads();
  m = fmaxf(fmaxf(red[0], red[1]), fmaxf(red[2], red[3]));
  float sum = 0.f;
#pragma unroll
  for (int j = 0; j < 8; ++j) { v[j] = __expf(v[j] - m); sum += v[j]; }
#pragma unroll
  for (int off = 32; off > 0; off >>= 1) sum += __shfl_xor(sum, off);
  __syncthreads();
  if ((tid & 63) == 0) red[tid >> 6] = sum;
  __syncthreads();
  sum = red[0] + red[1] + red[2] + red[3];
  const float inv = 1.0f / sum;
  half8 h;
#pragma unroll
  for (int j = 0; j < 8; ++j) h[j] = (_Float16)(v[j] * inv);
  *(half8*)(s + tid * 8) = h;
}

extern "C" void kernel_launch(void* const* d_in, const int* in_sizes, int n_in,
                              void* d_out, int out_size, void* d_ws, size_t ws_size,
                              hipStream_t stream) {
  (void)in_sizes; (void)n_in; (void)out_size;
  const float* x  = (const float*)d_in[0];
  const float* Wq = (const float*)d_in[1];
  const float* bq = (const float*)d_in[2];
  const float* Wk = (const float*)d_in[3];
  const float* bk = (const float*)d_in[4];
  const float* Wv = (const float*)d_in[5];
  const float* bv = (const float*)d_in[6];
  float* out = (float*)d_out;

  char* ws = (char*)d_ws;
  size_t off = 0;
  auto alloc = [&](size_t bytes) {
    char* p = ws + off;
    off += (bytes + 255) & ~255ull;
    return p;
  };
  _Float16* x16  = (_Float16*)alloc(8192ull * 1024 * 2);       // 16 MB
  _Float16* W16  = (_Float16*)alloc(3ull * 1024 * 1024 * 2);   // 6 MB (q|k|v)
  _Float16* QKV  = (_Float16*)alloc(3ull * 8192 * 1024 * 2);   // 48 MB (Q|K|V)
  _Float16* Vt   = (_Float16*)alloc(8192ull * 1024 * 2);       // 16 MB
  _Float16* Sc   = (_Float16*)alloc(4ull * 2048 * 2048 * 2);   // 32 MB
  if (off > ws_size) return;

  cvt_f32_f16<<<2048, 256, 0, stream>>>(x, x16, 8192 * 1024 / 8);
  cvt3_w<<<dim3(512, 3), 256, 0, stream>>>(Wq, Wk, Wv, W16);

  gemm2p<0><<<768, 512, 0, stream>>>(x16, W16, QKV, bq, bk, bv);
  transpose_v<<<dim3(32, 64, 4), 256, 0, stream>>>(QKV + 2ull * 8388608, Vt);

  gemm8p_sc<<<256, 512, 0, stream>>>(QKV, QKV + 8388608, Sc);
  softmax_rows_f16<<<8192, 256, 0, stream>>>(Sc);
  gemm2p<2><<<256, 512, 0, stream>>>(Sc, Vt, out, nullptr, nullptr, nullptr);
}

// Round 5
// 165.265 us; speedup vs baseline: 2.6499x; 1.0530x over previous
//
#include <hip/hip_runtime.h>

typedef _Float16 half8 __attribute__((ext_vector_type(8)));
typedef float floatx4 __attribute__((ext_vector_type(4)));

__device__ __forceinline__ void gld_lds16(const void* g, void* l) {
  __builtin_amdgcn_global_load_lds(
      (const __attribute__((address_space(1))) void*)g,
      (__attribute__((address_space(3))) void*)l, 16, 0, 0);
}

#define SB() __builtin_amdgcn_sched_barrier(0)
#define LGKM(n) asm volatile("s_waitcnt lgkmcnt(" #n ")" ::: "memory")
#define VMC(n) asm volatile("s_waitcnt vmcnt(" #n ")" ::: "memory")
#define PRIO1() __builtin_amdgcn_s_setprio(1)
#define PRIO0() __builtin_amdgcn_s_setprio(0)

// ===== counted-lgkm pipelined GEMM, C = A·B^T, f16 in, fp32 accum =====
// MODE 0: QKV  A=x16[8192,1024] B=Wcat[3072,1024] -> C f16 [8192,3072]+bias, 512 wg, tile 256x192
// MODE 1: SC   A=B=QKV (Q cols 0-1023 / K cols 1024-2047, stride 3072) -> f16 scores, 256 wg, tile 256x256
// MODE 2: PV   A=Sc[z][2048,2048] B=Vt[z][1024,2048] -> f32 out, 256 wg, tile 256x128
// Per K-tile: issue all ds_reads (FIFO-counted) -> stage A(t+1) -> MFMA quads
// gated by descending lgkmcnt -> mid-barrier -> stage B(t+2) -> last quad ->
// counted vmcnt -> end-barrier.  Barriers: 3/tile.  vmcnt never 0 mid-loop.
template <int MODE>
__global__ __launch_bounds__(512, 2) void gemm4(
    const _Float16* __restrict__ Ag, const _Float16* __restrict__ Bg,
    void* __restrict__ Cg, const float* __restrict__ bcat) {
  constexpr int TN   = MODE == 0 ? 192 : (MODE == 1 ? 256 : 128);
  constexpr int STR  = MODE == 0 ? 1024 : (MODE == 1 ? 3072 : 2048);
  constexpr int NK   = (MODE == 2 ? 2048 : 1024) / 64;
  constexpr int NWG  = MODE == 0 ? 512 : 256;
  constexpr int NBC  = TN / 64;   // B chunks per tile: 3 / 4 / 2
  constexpr int BBUF = TN * 64;   // elems per B buffer
  constexpr int CSTR = MODE == 0 ? 3072 : (MODE == 1 ? 2048 : 1024);

  int g = (int)blockIdx.x;
  g = (g & 7) * (NWG / 8) + (g >> 3);  // XCD swizzle (NWG % 8 == 0)

  int row0, col0;
  const _Float16 *Ap, *Bp;
  _Float16* C16 = nullptr;
  float* C32 = nullptr;
  if constexpr (MODE == 0) {
    const int tm = g >> 4, tn = g & 15;
    row0 = tm * 256; col0 = tn * 192;
    Ap = Ag + (size_t)row0 * 1024;
    Bp = Bg + (size_t)col0 * 1024;
    C16 = (_Float16*)Cg;
  } else if constexpr (MODE == 1) {
    const int z = g >> 6, r = g & 63, tm = r >> 3, tn = r & 7;
    row0 = tm * 256; col0 = tn * 256;
    Ap = Ag + (size_t)z * 6291456 + (size_t)row0 * 3072;
    Bp = Ag + (size_t)z * 6291456 + (size_t)col0 * 3072 + 1024;
    C16 = (_Float16*)Cg + (size_t)z * 4194304;
  } else {
    const int z = g >> 6, r = g & 63, tm = r >> 3, tn = r & 7;
    row0 = tm * 256; col0 = tn * 128;
    Ap = Ag + (size_t)z * 4194304 + (size_t)row0 * 2048;
    Bp = Bg + (size_t)z * 2097152 + (size_t)col0 * 2048;
    C32 = (float*)Cg + (size_t)z * 2097152;
  }

  __shared__ _Float16 lds[32768 + 2 * BBUF];  // A dbuf 64KB + B dbuf
  const int tid = threadIdx.x, lane = tid & 63, wid = tid >> 6;
  const int wave_m = MODE == 2 ? (wid >> 1) : (wid >> 2);
  const int wave_n = MODE == 2 ? (wid & 1) : (wid & 3);
  const int fr = lane & 15, u = lane >> 4, w7 = lane & 7;
  const int k0e = ((u ^ w7) << 3), k1e = (((4 + u) ^ w7) << 3);
  const int sgl = (((tid & 7) ^ ((tid >> 3) & 7)) << 3);
  const int srow = tid >> 3;

  floatx4 acc[MODE == 2 ? 4 : 8][MODE == 0 ? 3 : 4] = {};
  half8 aF0[8], aF1[8], bF0[4], bF1[4];

  // one gld per thread: 64 rows x 64 cols f16, XOR-swizzled source
  auto stage1 = [&](const _Float16* Gp, int r0c, int kt, int dst) {
    gld_lds16(Gp + (size_t)(r0c + srow) * STR + kt + sgl, &lds[dst + tid * 8]);
  };
  auto ldAq = [&](int bufA, int qm, half8* dst) {  // 8 x ds_read_b128
    const int rb = MODE == 2 ? wave_m * 64 : (wave_m * 128 + qm * 64);
#pragma unroll
    for (int mf = 0; mf < 4; ++mf) {
      const int ro = bufA + (rb + mf * 16 + fr) * 64;
      dst[mf * 2 + 0] = *(const half8*)&lds[ro + k0e];
      dst[mf * 2 + 1] = *(const half8*)&lds[ro + k1e];
    }
  };
  auto ldB2 = [&](int bufB, int qh, half8* dst) {  // 4 x ds_read_b128
    const int cb = (MODE == 0 ? wave_n * 48 : wave_n * 64) + qh * 32;
#pragma unroll
    for (int nf = 0; nf < 2; ++nf) {
      const int ro = bufB + (cb + nf * 16 + fr) * 64;
      dst[nf * 2 + 0] = *(const half8*)&lds[ro + k0e];
      dst[nf * 2 + 1] = *(const half8*)&lds[ro + k1e];
    }
  };
  auto ldB1 = [&](int bufB, half8* dst) {  // 2 x ds_read_b128 (MODE0 nf=2)
    const int ro = bufB + (wave_n * 48 + 32 + fr) * 64;
    dst[0] = *(const half8*)&lds[ro + k0e];
    dst[1] = *(const half8*)&lds[ro + k1e];
  };
  auto QUADx2 = [&](int am0, half8* aF, int nb, half8* bF) {  // 16 MFMA
#pragma unroll
    for (int mf = 0; mf < 4; ++mf)
#pragma unroll
      for (int nf = 0; nf < 2; ++nf)
#pragma unroll
        for (int kk = 0; kk < 2; ++kk)
          acc[am0 + mf][nb + nf] = __builtin_amdgcn_mfma_f32_16x16x32_f16(
              aF[mf * 2 + kk], bF[nf * 2 + kk], acc[am0 + mf][nb + nf], 0, 0, 0);
  };
  auto QUADx1 = [&](int am0, half8* aF, half8* bF) {  // 8 MFMA (MODE0)
#pragma unroll
    for (int mf = 0; mf < 4; ++mf)
#pragma unroll
      for (int kk = 0; kk < 2; ++kk)
        acc[am0 + mf][2] = __builtin_amdgcn_mfma_f32_16x16x32_f16(
            aF[mf * 2 + kk], bF[kk], acc[am0 + mf][2], 0, 0, 0);
  };

  // prologue: A(0)->p0, B(0)->p0, B(1)->p1; wait leaves B(1) in flight
#pragma unroll
  for (int c = 0; c < 4; ++c) stage1(Ap, c * 64, 0, c * 4096);
#pragma unroll
  for (int c = 0; c < NBC; ++c) stage1(Bp, c * 64, 0, 32768 + c * 4096);
#pragma unroll
  for (int c = 0; c < NBC; ++c) stage1(Bp, c * 64, 64, 32768 + BBUF + c * 4096);
  if constexpr (NBC == 4) VMC(4); else if constexpr (NBC == 3) VMC(3); else VMC(2);
  __builtin_amdgcn_s_barrier();

#pragma unroll 1
  for (int t = 0; t < NK; ++t) {
    const int kt = t * 64;
    const int bufA = (t & 1) * 16384, obufA = ((t + 1) & 1) * 16384;
    const int bufB = 32768 + (t & 1) * BBUF;
    // ---- issue all ds_reads for tile t (FIFO order pinned by SB) ----
    ldAq(bufA, 0, aF0); SB();
    ldB2(bufB, 0, bF0); SB();
    if constexpr (MODE == 0) { ldB1(bufB, bF1); } else { ldB2(bufB, 1, bF1); }
    SB();
    if constexpr (MODE != 2) { ldAq(bufA, 1, aF1); SB(); }
    // ---- stage A(t+1) into other parity (vmcnt FIFO: A first) ----
    if (t + 1 < NK) {
#pragma unroll
      for (int c = 0; c < 4; ++c) stage1(Ap, c * 64, kt + 64, obufA + c * 4096);
    }
    SB();
    // ---- MFMA quads gated by descending lgkmcnt ----
    if constexpr (MODE == 2) {
      // issued: aF0(8) bF0(4) bF1(4) = 16
      LGKM(4); SB(); PRIO1(); QUADx2(0, aF0, 0, bF0); PRIO0(); SB();
      LGKM(0); SB();
      __builtin_amdgcn_s_barrier();  // all waves done reading B(t)/A(t)
      if (t + 2 < NK) {
#pragma unroll
        for (int c = 0; c < 2; ++c) stage1(Bp, c * 64, kt + 128, bufB + c * 4096);
      }
      SB();
      PRIO1(); QUADx2(0, aF0, 2, bF1); PRIO0(); SB();
    } else if constexpr (MODE == 1) {
      // issued: aF0(8) bF0(4) bF1(4) aF1(8) = 24
      LGKM(12); SB(); PRIO1(); QUADx2(0, aF0, 0, bF0); PRIO0(); SB();
      LGKM(8);  SB(); PRIO1(); QUADx2(0, aF0, 2, bF1); PRIO0(); SB();
      LGKM(0);  SB(); PRIO1(); QUADx2(4, aF1, 0, bF0); PRIO0(); SB();
      __builtin_amdgcn_s_barrier();
      if (t + 2 < NK) {
#pragma unroll
        for (int c = 0; c < 4; ++c) stage1(Bp, c * 64, kt + 128, bufB + c * 4096);
      }
      SB();
      PRIO1(); QUADx2(4, aF1, 2, bF1); PRIO0(); SB();
    } else {
      // issued: aF0(8) bF0(4) bF1(2) aF1(8) = 22
      LGKM(10); SB(); PRIO1(); QUADx2(0, aF0, 0, bF0); PRIO0(); SB();
      LGKM(8);  SB(); PRIO1(); QUADx1(0, aF0, bF1); PRIO0(); SB();
      LGKM(0);  SB(); PRIO1(); QUADx2(4, aF1, 0, bF0); PRIO0(); SB();
      __builtin_amdgcn_s_barrier();
      if (t + 2 < NK) {
#pragma unroll
        for (int c = 0; c < 3; ++c) stage1(Bp, c * 64, kt + 128, bufB + c * 4096);
      }
      SB();
      PRIO1(); QUADx1(4, aF1, bF1); PRIO0(); SB();
    }
    // ---- counted end wait: leave only B(t+2) in flight ----
    if (t + 1 < NK) {
      if (t + 2 < NK) {
        if constexpr (NBC == 4) VMC(4); else if constexpr (NBC == 3) VMC(3); else VMC(2);
      } else VMC(0);
    }
    __builtin_amdgcn_s_barrier();
  }

  // ---- epilogue ----
  const int r0 = row0 + (MODE == 2 ? wave_m * 64 : wave_m * 128) + u * 4;
  const int c0 = col0 + (MODE == 0 ? wave_n * 48 : wave_n * 64) + fr;
  constexpr int NMT = MODE == 2 ? 4 : 8;
  constexpr int NFT = MODE == 0 ? 3 : 4;
#pragma unroll
  for (int m = 0; m < NMT; ++m)
#pragma unroll
    for (int n = 0; n < NFT; ++n) {
      const int col = c0 + n * 16;
      float badd = 0.f;
      if constexpr (MODE == 0) badd = bcat[col];
#pragma unroll
      for (int j = 0; j < 4; ++j) {
        const int row = r0 + m * 16 + j;
        if constexpr (MODE == 2)
          C32[(size_t)row * 1024 + col] = acc[m][n][j];
        else
          C16[(size_t)row * CSTR + col] = (_Float16)(acc[m][n][j] + badd);
      }
    }
}

// ---------------------------------------------------------------------------
__global__ void cvt_f32_f16(const float* __restrict__ in, _Float16* __restrict__ out, int n8) {
  int i = blockIdx.x * blockDim.x + threadIdx.x;
  const int stride = gridDim.x * blockDim.x;
  for (; i < n8; i += stride) {
    const float4* p = (const float4*)(in + (size_t)i * 8);
    float4 a = p[0], b = p[1];
    half8 h;
    h[0] = (_Float16)a.x; h[1] = (_Float16)a.y; h[2] = (_Float16)a.z; h[3] = (_Float16)a.w;
    h[4] = (_Float16)b.x; h[5] = (_Float16)b.y; h[6] = (_Float16)b.z; h[7] = (_Float16)b.w;
    *(half8*)(out + (size_t)i * 8) = h;
  }
}

// 3 weight matrices f32->f16 concat [3072,1024]; grid (512,3)
__global__ void cvt3_w(const float* __restrict__ wq, const float* __restrict__ wk,
                       const float* __restrict__ wv, _Float16* __restrict__ out) {
  const float* in = blockIdx.y == 0 ? wq : (blockIdx.y == 1 ? wk : wv);
  _Float16* o = out + (size_t)blockIdx.y * 1048576;
  const int i = blockIdx.x * blockDim.x + threadIdx.x;
  const float4* p = (const float4*)(in + (size_t)i * 8);
  float4 a = p[0], b = p[1];
  half8 h;
  h[0] = (_Float16)a.x; h[1] = (_Float16)a.y; h[2] = (_Float16)a.z; h[3] = (_Float16)a.w;
  h[4] = (_Float16)b.x; h[5] = (_Float16)b.y; h[6] = (_Float16)b.z; h[7] = (_Float16)b.w;
  *(half8*)(o + (size_t)i * 8) = h;
}

__global__ void bias_cat(const float* __restrict__ a, const float* __restrict__ b,
                         const float* __restrict__ c, float* __restrict__ o) {
  const int i = blockIdx.x * 256 + threadIdx.x;  // grid 12 -> 3072
  const float* s = i < 1024 ? a : (i < 2048 ? b : c);
  o[i] = s[i & 1023];
}

// V = QKV cols 2048.. (stride 3072) -> Vt[4][1024][2048]
__global__ __launch_bounds__(256) void transpose_v(const _Float16* __restrict__ QKV,
                                                   _Float16* __restrict__ Vt) {
  __shared__ _Float16 t[32][36];
  const int b = blockIdx.z;
  const int e0 = blockIdx.x * 32;
  const int s0 = blockIdx.y * 32;
  const int tid = threadIdx.x;
  const int r = tid >> 3;
  const int c4 = (tid & 7) * 4;
  const _Float16* src = QKV + (size_t)(b * 2048 + s0 + r) * 3072 + 2048 + e0 + c4;
#pragma unroll
  for (int j = 0; j < 4; ++j) t[r][c4 + j] = src[j];
  __syncthreads();
  _Float16* dst = Vt + ((size_t)b * 1024 + e0 + r) * 2048 + s0 + c4;
#pragma unroll
  for (int j = 0; j < 4; ++j) dst[j] = t[c4 + j][r];
}

// in-place row softmax over f16 scores, one block per row of 2048
__global__ __launch_bounds__(256) void softmax_rows_f16(_Float16* __restrict__ S) {
  __shared__ float red[4];
  _Float16* s = S + (size_t)blockIdx.x * 2048;
  const int tid = threadIdx.x;
  float v[8];
  {
    half8 h = *(const half8*)(s + tid * 8);
#pragma unroll
    for (int j = 0; j < 8; ++j) v[j] = (float)h[j];
  }
  float m = v[0];
#pragma unroll
  for (int j = 1; j < 8; ++j) m = fmaxf(m, v[j]);
#pragma unroll
  for (int off = 32; off > 0; off >>= 1) m = fmaxf(m, __shfl_xor(m, off));
  if ((tid & 63) == 0) red[tid >> 6] = m;
  __syncthreads();
  m = fmaxf(fmaxf(red[0], red[1]), fmaxf(red[2], red[3]));
  float sum = 0.f;
#pragma unroll
  for (int j = 0; j < 8; ++j) { v[j] = __expf(v[j] - m); sum += v[j]; }
#pragma unroll
  for (int off = 32; off > 0; off >>= 1) sum += __shfl_xor(sum, off);
  __syncthreads();
  if ((tid & 63) == 0) red[tid >> 6] = sum;
  __syncthreads();
  sum = red[0] + red[1] + red[2] + red[3];
  const float inv = 1.0f / sum;
  half8 h;
#pragma unroll
  for (int j = 0; j < 8; ++j) h[j] = (_Float16)(v[j] * inv);
  *(half8*)(s + tid * 8) = h;
}

extern "C" void kernel_launch(void* const* d_in, const int* in_sizes, int n_in,
                              void* d_out, int out_size, void* d_ws, size_t ws_size,
                              hipStream_t stream) {
  (void)in_sizes; (void)n_in; (void)out_size;
  const float* x  = (const float*)d_in[0];
  const float* Wq = (const float*)d_in[1];
  const float* bq = (const float*)d_in[2];
  const float* Wk = (const float*)d_in[3];
  const float* bk = (const float*)d_in[4];
  const float* Wv = (const float*)d_in[5];
  const float* bv = (const float*)d_in[6];
  float* out = (float*)d_out;

  char* ws = (char*)d_ws;
  size_t off = 0;
  auto alloc = [&](size_t bytes) {
    char* p = ws + off;
    off += (bytes + 255) & ~255ull;
    return p;
  };
  _Float16* x16  = (_Float16*)alloc(8192ull * 1024 * 2);       // 16 MB
  _Float16* W16  = (_Float16*)alloc(3072ull * 1024 * 2);       // 6 MB concat
  _Float16* QKV  = (_Float16*)alloc(8192ull * 3072 * 2);       // 48 MB [8192,3072]
  _Float16* Vt   = (_Float16*)alloc(4096ull * 1024 * 4);       // 16 MB [4][1024][2048]
  _Float16* Sc   = (_Float16*)alloc(4ull * 2048 * 2048 * 2);   // 32 MB
  float*    bcat = (float*)alloc(3072 * 4);
  if (off > ws_size) return;

  cvt_f32_f16<<<2048, 256, 0, stream>>>(x, x16, 8192 * 1024 / 8);
  cvt3_w<<<dim3(512, 3), 256, 0, stream>>>(Wq, Wk, Wv, W16);
  bias_cat<<<12, 256, 0, stream>>>(bq, bk, bv, bcat);

  gemm4<0><<<512, 512, 0, stream>>>(x16, W16, QKV, bcat);
  transpose_v<<<dim3(32, 64, 4), 256, 0, stream>>>(QKV, Vt);

  gemm4<1><<<256, 512, 0, stream>>>(QKV, QKV, Sc, nullptr);
  softmax_rows_f16<<<8192, 256, 0, stream>>>(Sc);
  gemm4<2><<<256, 512, 0, stream>>>(Sc, Vt, out, nullptr);
}